// Round 10
// baseline (830.483 us; speedup 1.0000x reference)
//
#include <hip/hip_runtime.h>
#include <hip/hip_bf16.h>
#include <math.h>

#define DEV __device__ __forceinline__

typedef __attribute__((ext_vector_type(8))) short bf16x8;
typedef __attribute__((ext_vector_type(4))) short s16x4;
typedef __attribute__((ext_vector_type(4))) float f32x4;

// fast tanh-form GELU: x * sigmoid(1.5957691*x*(1+0.044715x^2))
DEV float gelu_f(float x) {
  float u = 1.5957691f * x * (1.0f + 0.044715f * x * x);
  return x / (1.0f + __expf(-u));
}

DEV short bf16s(float x) {
  __hip_bfloat16 v = __float2bfloat16(x);
  return *reinterpret_cast<short*>(&v);
}

// async 16B global->LDS (gfx950). dest = wave-uniform base + lane*16.
DEV void async16(void* lds, const void* g) {
  __builtin_amdgcn_global_load_lds(
      (const __attribute__((address_space(1))) unsigned int*)g,
      (__attribute__((address_space(3))) unsigned int*)lds, 16, 0, 0);
}

// ---------- fused conversions ----------
__global__ __launch_bounds__(256) void conv2_kernel(
    const float* __restrict__ X1, __hip_bfloat16* __restrict__ Y1,
    const float* __restrict__ X2, __hip_bfloat16* __restrict__ Y2, int n) {
  int i = blockIdx.x * 256 + threadIdx.x;
  if (i < n) {
    Y1[i] = __float2bfloat16(X1[i]);
    Y2[i] = __float2bfloat16(X2[i]);
  }
}

struct CvArgs {
  const float* s[11];
  __hip_bfloat16* d[11];
};

__global__ __launch_bounds__(256) void multi_tconv_kernel(CvArgs a) {
  const int Rj[11] = {256, 512, 512, 512, 2048, 256, 512, 512, 512, 512, 2048};
  const int Cj[11] = {512, 1536, 512, 2048, 512, 512, 512, 1536, 512, 2048, 512};
  const int Nj[11] = {1, 4, 4, 4, 4, 1, 1, 1, 1, 1, 1};
  __shared__ float t[32][33];
  int rem = blockIdx.x, j = 0;
  for (; j < 11; ++j) {
    int tj = (Rj[j] >> 5) * (Cj[j] >> 5) * Nj[j];
    if (rem < tj) break;
    rem -= tj;
  }
  const int R = Rj[j], C = Cj[j];
  const int perb = (R >> 5) * (C >> 5);
  const int z = rem / perb;
  const int tt = rem % perb;
  const int tc = C >> 5;
  const int r0 = (tt / tc) << 5, c0 = (tt % tc) << 5;
  const float* xb = a.s[j] + (size_t)z * R * C;
  __hip_bfloat16* yb = a.d[j] + (size_t)z * R * C;
  int tx = threadIdx.x & 31, ty = threadIdx.x >> 5;
  for (int i = ty; i < 32; i += 8) t[i][tx] = xb[(size_t)(r0 + i) * C + c0 + tx];
  __syncthreads();
  for (int i = ty; i < 32; i += 8)
    yb[(size_t)(c0 + i) * R + r0 + tx] = __float2bfloat16(t[tx][i]);
}

__global__ __launch_bounds__(256) void build_s_kernel(
    const float* __restrict__ W, __hip_bfloat16* __restrict__ S, int D, int Kk) {
  int i = blockIdx.x * 256 + threadIdx.x;
  if (i >= D * D) return;
  int d = i / D, e = i % D;
  float s = 0.f;
  for (int k = 0; k < Kk; ++k) {
    s += W[(size_t)k * D * D + i];
    s += W[(size_t)k * D * D + (size_t)e * D + d];
  }
  S[i] = __float2bfloat16(s / (2.0f * Kk));
}

// ---------- MFMA GEMM A: 64x64 tile, dbuf (32KB). For small-M N=512 GEMMs. ----------
__global__ __launch_bounds__(256) void mgemm64_kernel(
    const __hip_bfloat16* __restrict__ A, const __hip_bfloat16* __restrict__ Bt,
    const float* __restrict__ bias, const float* __restrict__ resid,
    float* __restrict__ outf, __hip_bfloat16* __restrict__ outb,
    int M, int N, int K, int act, int mgrp) {
  __shared__ __align__(16) short As[2][64 * 64];
  __shared__ __align__(16) short Bs[2][64 * 64];
  const int tid = threadIdx.x;
  const int lane = tid & 63, wave = tid >> 6;
  const int quad = lane >> 4, l15 = lane & 15;
  const int bid = blockIdx.x;
  const int g = bid & 7, sidx = bid >> 3;
  const int mt = g * mgrp + sidx % mgrp;
  const int nt = sidx / mgrp;
  const int row0 = mt * 64, col0 = nt * 64;
  const short* Ag = (const short*)A;
  const short* Bg = (const short*)Bt;

  auto stage = [&](int bsel, int k0) {
#pragma unroll
    for (int i = 0; i < 2; ++i) {
      int c = (wave * 2 + i) * 64 + lane;
      int r = c >> 3, pp = c & 7;
      int kc = pp ^ (r & 7);
      async16(&As[bsel][(wave * 2 + i) * 512], &Ag[(size_t)(row0 + r) * K + k0 + kc * 8]);
      async16(&Bs[bsel][(wave * 2 + i) * 512], &Bg[(size_t)(col0 + r) * K + k0 + kc * 8]);
    }
  };

  f32x4 acc[4] = {};
  const int nk = K >> 6;
  stage(0, 0);
  for (int t = 0; t < nk; ++t) {
    const int cur = t & 1;
    __syncthreads();  // drains loads for buf cur
    if (t + 1 < nk) stage(cur ^ 1, (t + 1) << 6);
#pragma unroll
    for (int kh = 0; kh < 2; ++kh) {
      const int ch = ((quad + kh * 4) ^ (l15 & 7)) * 8;
      bf16x8 af = *(const bf16x8*)&As[cur][(wave * 16 + l15) * 64 + ch];
#pragma unroll
      for (int ni = 0; ni < 4; ++ni) {
        bf16x8 bq = *(const bf16x8*)&Bs[cur][(ni * 16 + l15) * 64 + ch];
        acc[ni] = __builtin_amdgcn_mfma_f32_16x16x32_bf16(af, bq, acc[ni], 0, 0, 0);
      }
    }
  }

#pragma unroll
  for (int ni = 0; ni < 4; ++ni) {
    int cc = col0 + ni * 16 + l15;
    float bb = bias ? bias[cc] : 0.f;
#pragma unroll
    for (int r = 0; r < 4; ++r) {
      int rr = row0 + wave * 16 + quad * 4 + r;
      size_t idx = (size_t)rr * N + cc;
      float v = acc[ni][r] + bb;
      if (act) v = gelu_f(v);
      if (resid) v += resid[idx];
      if (outf) outf[idx] = v;
      if (outb) outb[idx] = __float2bfloat16(v);
    }
  }
}

// ---------- MFMA GEMM A-pipe: 64x64 tile, 3-buffer depth-2 pipeline with COUNTED
// vmcnt (48KB -> 3 blocks/CU). Each stage = 4 load-insts/wave; wait vmcnt(4) keeps
// next tile's loads in flight across the barrier; vmcnt(0) only at last step.
// Buffer (t+2)%3 == (t-1)%3, whose reads complete before iter-t barrier. ----------
__global__ __launch_bounds__(256) void mgemm64p_kernel(
    const __hip_bfloat16* __restrict__ A, const __hip_bfloat16* __restrict__ Bt,
    const float* __restrict__ bias, const float* __restrict__ resid,
    float* __restrict__ outf, __hip_bfloat16* __restrict__ outb,
    int M, int N, int K, int act, int mgrp) {
  __shared__ __align__(16) short As[3][64 * 64];
  __shared__ __align__(16) short Bs[3][64 * 64];
  const int tid = threadIdx.x;
  const int lane = tid & 63, wave = tid >> 6;
  const int quad = lane >> 4, l15 = lane & 15;
  const int bid = blockIdx.x;
  const int g = bid & 7, sidx = bid >> 3;
  const int mt = g * mgrp + sidx % mgrp;
  const int nt = sidx / mgrp;
  const int row0 = mt * 64, col0 = nt * 64;
  const short* Ag = (const short*)A;
  const short* Bg = (const short*)Bt;

  auto stage = [&](int bsel, int k0) {
#pragma unroll
    for (int i = 0; i < 2; ++i) {
      int c = (wave * 2 + i) * 64 + lane;
      int r = c >> 3, pp = c & 7;
      int kc = pp ^ (r & 7);
      async16(&As[bsel][(wave * 2 + i) * 512], &Ag[(size_t)(row0 + r) * K + k0 + kc * 8]);
      async16(&Bs[bsel][(wave * 2 + i) * 512], &Bg[(size_t)(col0 + r) * K + k0 + kc * 8]);
    }
  };

  f32x4 acc[4] = {};
  const int nk = K >> 6;  // >= 8 for all routed shapes
  stage(0, 0);
  stage(1, 64);
  int cur = 0, nb = 2;  // buffer to read; buffer to stage (t+2)
  for (int t = 0; t < nk; ++t) {
    if (t + 1 < nk)
      asm volatile("s_waitcnt vmcnt(4)" ::: "memory");
    else
      asm volatile("s_waitcnt vmcnt(0)" ::: "memory");
    __builtin_amdgcn_s_barrier();
    if (t + 2 < nk) stage(nb, (t + 2) << 6);
#pragma unroll
    for (int kh = 0; kh < 2; ++kh) {
      const int ch = ((quad + kh * 4) ^ (l15 & 7)) * 8;
      bf16x8 af = *(const bf16x8*)&As[cur][(wave * 16 + l15) * 64 + ch];
#pragma unroll
      for (int ni = 0; ni < 4; ++ni) {
        bf16x8 bq = *(const bf16x8*)&Bs[cur][(ni * 16 + l15) * 64 + ch];
        acc[ni] = __builtin_amdgcn_mfma_f32_16x16x32_bf16(af, bq, acc[ni], 0, 0, 0);
      }
    }
    cur = (cur == 2) ? 0 : cur + 1;
    nb = (nb == 2) ? 0 : nb + 1;
  }

#pragma unroll
  for (int ni = 0; ni < 4; ++ni) {
    int cc = col0 + ni * 16 + l15;
    float bb = bias ? bias[cc] : 0.f;
#pragma unroll
    for (int r = 0; r < 4; ++r) {
      int rr = row0 + wave * 16 + quad * 4 + r;
      size_t idx = (size_t)rr * N + cc;
      float v = acc[ni][r] + bb;
      if (act) v = gelu_f(v);
      if (resid) v += resid[idx];
      if (outf) outf[idx] = v;
      if (outb) outb[idx] = __float2bfloat16(v);
    }
  }
}

// ---------- MFMA GEMM B: 128x64 tile, 4 waves, dbuf 48KB -> 3 blocks/CU. ----------
__global__ __launch_bounds__(256) void mgemm128_kernel(
    const __hip_bfloat16* __restrict__ A, const __hip_bfloat16* __restrict__ Bt,
    const float* __restrict__ bias, const float* __restrict__ resid,
    float* __restrict__ outf, __hip_bfloat16* __restrict__ outb,
    int M, int N, int K, int act, int mgrp) {
  __shared__ __align__(16) short As[2][128 * 64];
  __shared__ __align__(16) short Bs[2][64 * 64];
  const int tid = threadIdx.x;
  const int lane = tid & 63, wave = tid >> 6;
  const int quad = lane >> 4, l15 = lane & 15;
  const int wr = wave >> 1, wc = wave & 1;  // 2x2 wave grid: 64 rows x 32 cols each
  const int bid = blockIdx.x;
  const int g = bid & 7, sidx = bid >> 3;
  const int mt = g * mgrp + sidx % mgrp;
  const int nt = sidx / mgrp;
  const int row0 = mt * 128, col0 = nt * 64;
  const short* Ag = (const short*)A;
  const short* Bg = (const short*)Bt;

  auto stage = [&](int bsel, int k0) {
#pragma unroll
    for (int i = 0; i < 4; ++i) {  // A: 128 rows x 64 cols = 1024 chunks
      int c = i * 256 + tid;
      int r = c >> 3, pp = c & 7;
      int kc = pp ^ (r & 7);
      async16(&As[bsel][c * 8], &Ag[(size_t)(row0 + r) * K + k0 + kc * 8]);
    }
#pragma unroll
    for (int i = 0; i < 2; ++i) {  // B: 64 rows x 64 cols = 512 chunks
      int c = i * 256 + tid;
      int r = c >> 3, pp = c & 7;
      int kc = pp ^ (r & 7);
      async16(&Bs[bsel][c * 8], &Bg[(size_t)(col0 + r) * K + k0 + kc * 8]);
    }
  };

  f32x4 acc[4][2] = {};
  const int nk = K >> 6;
  stage(0, 0);
  for (int t = 0; t < nk; ++t) {
    const int cur = t & 1;
    __syncthreads();
    if (t + 1 < nk) stage(cur ^ 1, (t + 1) << 6);
#pragma unroll
    for (int kh = 0; kh < 2; ++kh) {
      const int ch = ((quad + kh * 4) ^ (l15 & 7)) * 8;
      bf16x8 af[4], bq[2];
#pragma unroll
      for (int mi = 0; mi < 4; ++mi)
        af[mi] = *(const bf16x8*)&As[cur][(wr * 64 + mi * 16 + l15) * 64 + ch];
#pragma unroll
      for (int ni = 0; ni < 2; ++ni)
        bq[ni] = *(const bf16x8*)&Bs[cur][(wc * 32 + ni * 16 + l15) * 64 + ch];
#pragma unroll
      for (int mi = 0; mi < 4; ++mi)
#pragma unroll
        for (int ni = 0; ni < 2; ++ni)
          acc[mi][ni] = __builtin_amdgcn_mfma_f32_16x16x32_bf16(af[mi], bq[ni], acc[mi][ni], 0, 0, 0);
    }
  }

#pragma unroll
  for (int ni = 0; ni < 2; ++ni) {
    int cc = col0 + wc * 32 + ni * 16 + l15;
    float bb = bias ? bias[cc] : 0.f;
#pragma unroll
    for (int mi = 0; mi < 4; ++mi) {
#pragma unroll
      for (int r = 0; r < 4; ++r) {
        int rr = row0 + wr * 64 + mi * 16 + quad * 4 + r;
        size_t idx = (size_t)rr * N + cc;
        float v = acc[mi][ni][r] + bb;
        if (act) v = gelu_f(v);
        if (resid) v += resid[idx];
        if (outf) outf[idx] = v;
        if (outb) outb[idx] = __float2bfloat16(v);
      }
    }
  }
}

// ---------- MFMA GEMM C: 128x128 tile, 8 WAVES (512 thr), dbuf 64KB -> 2 blocks/CU.
// For FFN1 (N=2048: clean 512/1024 grids). Per-wave 64x32: 16 MFMA : 12 ds_read. ----------
__global__ __launch_bounds__(512) void mgemm_w8_kernel(
    const __hip_bfloat16* __restrict__ A, const __hip_bfloat16* __restrict__ Bt,
    const float* __restrict__ bias, const float* __restrict__ resid,
    float* __restrict__ outf, __hip_bfloat16* __restrict__ outb,
    int M, int N, int K, int act, int mgrp) {
  __shared__ __align__(16) short As[2][128 * 64];
  __shared__ __align__(16) short Bs[2][128 * 64];
  const int tid = threadIdx.x;
  const int lane = tid & 63, wave = tid >> 6;
  const int quad = lane >> 4, l15 = lane & 15;
  const int wr = wave >> 2, wc = wave & 3;  // 2x4 wave grid: 64 rows x 32 cols each
  const int bid = blockIdx.x;
  const int g = bid & 7, sidx = bid >> 3;
  const int mt = g * mgrp + sidx % mgrp;
  const int nt = sidx / mgrp;
  const int row0 = mt * 128, col0 = nt * 128;
  const short* Ag = (const short*)A;
  const short* Bg = (const short*)Bt;

  auto stage = [&](int bsel, int k0) {
#pragma unroll
    for (int i = 0; i < 2; ++i) {  // A: 128x64 = 1024 chunks over 512 threads
      int c = i * 512 + tid;
      int r = c >> 3, pp = c & 7;
      int kc = pp ^ (r & 7);
      async16(&As[bsel][c * 8], &Ag[(size_t)(row0 + r) * K + k0 + kc * 8]);
    }
#pragma unroll
    for (int i = 0; i < 2; ++i) {  // B: 128x64 = 1024 chunks
      int c = i * 512 + tid;
      int r = c >> 3, pp = c & 7;
      int kc = pp ^ (r & 7);
      async16(&Bs[bsel][c * 8], &Bg[(size_t)(col0 + r) * K + k0 + kc * 8]);
    }
  };

  f32x4 acc[4][2] = {};
  const int nk = K >> 6;
  stage(0, 0);
  for (int t = 0; t < nk; ++t) {
    const int cur = t & 1;
    __syncthreads();
    if (t + 1 < nk) stage(cur ^ 1, (t + 1) << 6);
#pragma unroll
    for (int kh = 0; kh < 2; ++kh) {
      const int ch = ((quad + kh * 4) ^ (l15 & 7)) * 8;
      bf16x8 af[4], bq[2];
#pragma unroll
      for (int mi = 0; mi < 4; ++mi)
        af[mi] = *(const bf16x8*)&As[cur][(wr * 64 + mi * 16 + l15) * 64 + ch];
#pragma unroll
      for (int ni = 0; ni < 2; ++ni)
        bq[ni] = *(const bf16x8*)&Bs[cur][(wc * 32 + ni * 16 + l15) * 64 + ch];
#pragma unroll
      for (int mi = 0; mi < 4; ++mi)
#pragma unroll
        for (int ni = 0; ni < 2; ++ni)
          acc[mi][ni] = __builtin_amdgcn_mfma_f32_16x16x32_bf16(af[mi], bq[ni], acc[mi][ni], 0, 0, 0);
    }
  }

#pragma unroll
  for (int ni = 0; ni < 2; ++ni) {
    int cc = col0 + wc * 32 + ni * 16 + l15;
    float bb = bias ? bias[cc] : 0.f;
#pragma unroll
    for (int mi = 0; mi < 4; ++mi) {
#pragma unroll
      for (int r = 0; r < 4; ++r) {
        int rr = row0 + wr * 64 + mi * 16 + quad * 4 + r;
        size_t idx = (size_t)rr * N + cc;
        float v = acc[mi][ni][r] + bb;
        if (act) v = gelu_f(v);
        if (resid) v += resid[idx];
        if (outf) outf[idx] = v;
        if (outb) outb[idx] = __float2bfloat16(v);
      }
    }
  }
}

// ---------- QKV GEMM (128x64 tile, 4 waves, dbuf 48KB -> 3 blk/CU) ----------
__global__ __launch_bounds__(256) void qkv_gemm_kernel(
    const __hip_bfloat16* __restrict__ A, const __hip_bfloat16* __restrict__ Bt,
    const float* __restrict__ bias, __hip_bfloat16* __restrict__ qkv,
    int M, int K, int nseq, int lgn, int mgrp) {
  __shared__ __align__(16) short As[2][128 * 64];
  __shared__ __align__(16) short Bs[2][64 * 64];
  const int tid = threadIdx.x;
  const int lane = tid & 63, wave = tid >> 6;
  const int quad = lane >> 4, l15 = lane & 15;
  const int wr = wave >> 1, wc = wave & 1;
  const int bid = blockIdx.x;
  const int g = bid & 7, sidx = bid >> 3;
  const int mt = g * mgrp + sidx % mgrp;
  const int nt = sidx / mgrp;
  const int row0 = mt * 128, col0 = nt * 64;
  const short* Ag = (const short*)A;
  const short* Bg = (const short*)Bt;

  auto stage = [&](int bsel, int k0) {
#pragma unroll
    for (int i = 0; i < 4; ++i) {
      int c = i * 256 + tid;
      int r = c >> 3, pp = c & 7;
      int kc = pp ^ (r & 7);
      async16(&As[bsel][c * 8], &Ag[(size_t)(row0 + r) * K + k0 + kc * 8]);
    }
#pragma unroll
    for (int i = 0; i < 2; ++i) {
      int c = i * 256 + tid;
      int r = c >> 3, pp = c & 7;
      int kc = pp ^ (r & 7);
      async16(&Bs[bsel][c * 8], &Bg[(size_t)(col0 + r) * K + k0 + kc * 8]);
    }
  };

  f32x4 acc[4][2] = {};
  const int nk = K >> 6;
  stage(0, 0);
  for (int t = 0; t < nk; ++t) {
    const int cur = t & 1;
    __syncthreads();
    if (t + 1 < nk) stage(cur ^ 1, (t + 1) << 6);
#pragma unroll
    for (int kh = 0; kh < 2; ++kh) {
      const int ch = ((quad + kh * 4) ^ (l15 & 7)) * 8;
      bf16x8 af[4], bq[2];
#pragma unroll
      for (int mi = 0; mi < 4; ++mi)
        af[mi] = *(const bf16x8*)&As[cur][(wr * 64 + mi * 16 + l15) * 64 + ch];
#pragma unroll
      for (int ni = 0; ni < 2; ++ni)
        bq[ni] = *(const bf16x8*)&Bs[cur][(wc * 32 + ni * 16 + l15) * 64 + ch];
#pragma unroll
      for (int mi = 0; mi < 4; ++mi)
#pragma unroll
        for (int ni = 0; ni < 2; ++ni)
          acc[mi][ni] = __builtin_amdgcn_mfma_f32_16x16x32_bf16(af[mi], bq[ni], acc[mi][ni], 0, 0, 0);
    }
  }

  const size_t PART = (size_t)M * 512;
#pragma unroll
  for (int ni = 0; ni < 2; ++ni) {
    int cc = col0 + wc * 32 + ni * 16 + l15;  // 0..1535
    float bb = bias ? bias[cc] : 0.f;
    int which = cc >> 9;
    int h = (cc >> 6) & 7;
    int d = cc & 63;
#pragma unroll
    for (int mi = 0; mi < 4; ++mi) {
#pragma unroll
      for (int r = 0; r < 4; ++r) {
        int rr = row0 + wr * 64 + mi * 16 + quad * 4 + r;
        int b = rr >> lgn;
        int nn = rr & (nseq - 1);
        float v = acc[mi][ni][r] + bb;
        size_t dst;
        if (which == 2) {
          dst = 2 * PART + (((size_t)b * 8 + h) * 64 + d) * nseq + nn;
        } else {
          dst = (size_t)which * PART + (((size_t)b * 8 + h) * nseq + nn) * 64 + d;
        }
        qkv[dst] = __float2bfloat16(v);
      }
    }
  }
}

// ---------- fused flash attention (MFMA, NO-MAX softmax, dbuf, XCD-local) ----------
__global__ __launch_bounds__(256) void fattn_kernel(
    const __hip_bfloat16* __restrict__ Qh, const __hip_bfloat16* __restrict__ Kh,
    const __hip_bfloat16* __restrict__ Vt, __hip_bfloat16* __restrict__ O,
    const __hip_bfloat16* __restrict__ Abias, const float* __restrict__ ebW,
    const float* __restrict__ ebs, int N, int lgq) {
  __shared__ __align__(16) short Ks[2][64 * 64];
  __shared__ __align__(16) short Vs[2][64 * 64];
  __shared__ __align__(16) short Ps[4][16][72];
  const int bid = blockIdx.x;
  const int g = bid & 7, s = bid >> 3;
  const int bloc = s >> (lgq + 3);
  const int rem = s & ((8 << lgq) - 1);
  const int h = rem >> lgq;
  const int qt = rem & ((1 << lgq) - 1);
  const int b = g * 2 + bloc;
  const int tid = threadIdx.x, lane = tid & 63, wave = tid >> 6;
  const int quad = lane >> 4, l15 = lane & 15;
  const size_t hb = (size_t)b * 8 + h;
  const short* Qg = (const short*)Qh + hb * N * 64;
  const short* Kg = (const short*)Kh + hb * N * 64;
  const short* Vg = (const short*)Vt + hb * 64 * N;
  const float scale = 0.125f;
  const bool hasb = (Abias != nullptr);
  const float bscale = hasb ? ebs[0] * ebW[h] : 0.f;
  const int qrow_w = qt * 64 + wave * 16;

  auto stageKV = [&](int bsel, int k0) {
#pragma unroll
    for (int i = 0; i < 2; ++i) {
      int c = (wave * 2 + i) * 64 + lane;
      int r = c >> 3, pp = c & 7;
      int kc = pp ^ (r & 7);
      async16(&Ks[bsel][(wave * 2 + i) * 512], &Kg[(size_t)(k0 + r) * 64 + kc * 8]);
      async16(&Vs[bsel][(wave * 2 + i) * 512], &Vg[(size_t)r * N + k0 + kc * 8]);
    }
  };

  bf16x8 qf[2];
  qf[0] = *(const bf16x8*)&Qg[(size_t)(qrow_w + l15) * 64 + quad * 8];
  qf[1] = *(const bf16x8*)&Qg[(size_t)(qrow_w + l15) * 64 + quad * 8 + 32];

  float l_r[4] = {0.f, 0.f, 0.f, 0.f};
  f32x4 oacc[4] = {};

  const int ntl = N >> 6;
  stageKV(0, 0);
  for (int t = 0; t < ntl; ++t) {
    const int cur = t & 1;
    const int k0 = t << 6;
    __syncthreads();
    if (t + 1 < ntl) stageKV(cur ^ 1, (t + 1) << 6);

    f32x4 sv[4] = {};
    __builtin_amdgcn_s_setprio(1);
#pragma unroll
    for (int kh = 0; kh < 2; ++kh) {
      const int ch = ((quad + kh * 4) ^ (l15 & 7)) * 8;
#pragma unroll
      for (int ni = 0; ni < 4; ++ni) {
        bf16x8 kf = *(const bf16x8*)&Ks[cur][(ni * 16 + l15) * 64 + ch];
        sv[ni] = __builtin_amdgcn_mfma_f32_16x16x32_bf16(qf[kh], kf, sv[ni], 0, 0, 0);
      }
    }
    __builtin_amdgcn_s_setprio(0);
    if (hasb) {
#pragma unroll
      for (int ni = 0; ni < 4; ++ni)
#pragma unroll
        for (int r = 0; r < 4; ++r) {
          int qq = qrow_w + quad * 4 + r;
          int kk = k0 + ni * 16 + l15;
          float ab = __bfloat162float(Abias[((size_t)b * N + qq) * N + kk]);
          sv[ni][r] = sv[ni][r] * scale + bscale * ab;
        }
    } else {
#pragma unroll
      for (int ni = 0; ni < 4; ++ni)
#pragma unroll
        for (int r = 0; r < 4; ++r) sv[ni][r] *= scale;
    }

    // no-max softmax numerator: p = exp(s); accumulate local row sums
#pragma unroll
    for (int ni = 0; ni < 4; ++ni)
#pragma unroll
      for (int r = 0; r < 4; ++r) {
        float p = __expf(sv[ni][r]);
        sv[ni][r] = p;
        l_r[r] += p;
      }

#pragma unroll
    for (int ni = 0; ni < 4; ++ni)
#pragma unroll
      for (int r = 0; r < 4; ++r)
        Ps[wave][quad * 4 + r][ni * 16 + l15] = bf16s(sv[ni][r]);

    bf16x8 pf0 = *(const bf16x8*)&Ps[wave][l15][quad * 8];
    bf16x8 pf1 = *(const bf16x8*)&Ps[wave][l15][quad * 8 + 32];
    __builtin_amdgcn_s_setprio(1);
#pragma unroll
    for (int kh = 0; kh < 2; ++kh) {
      const int ch = ((quad + kh * 4) ^ (l15 & 7)) * 8;
#pragma unroll
      for (int ni = 0; ni < 4; ++ni) {
        bf16x8 vf = *(const bf16x8*)&Vs[cur][(ni * 16 + l15) * 64 + ch];
        oacc[ni] = __builtin_amdgcn_mfma_f32_16x16x32_bf16(kh ? pf1 : pf0, vf, oacc[ni], 0, 0, 0);
      }
    }
    __builtin_amdgcn_s_setprio(0);
  }

  // reduce row sums across the 16-lane row group, then normalize
#pragma unroll
  for (int off = 1; off < 16; off <<= 1)
#pragma unroll
    for (int r = 0; r < 4; ++r) l_r[r] += __shfl_xor(l_r[r], off, 64);
  float inv[4];
#pragma unroll
  for (int r = 0; r < 4; ++r) inv[r] = 1.f / l_r[r];
#pragma unroll
  for (int ni = 0; ni < 4; ++ni)
#pragma unroll
    for (int r = 0; r < 4; ++r) {
      int nn = qrow_w + quad * 4 + r;
      int col = h * 64 + ni * 16 + l15;
      O[((size_t)b * N + nn) * 512 + col] = __float2bfloat16(oacc[ni][r] * inv[r]);
    }
}

// ---------- decoder: 64x64 tiles (dbuf), 36 triu pairs x 16 batches ----------
__global__ __launch_bounds__(256) void dec_mfma_kernel(
    const __hip_bfloat16* __restrict__ Tb_, const __hip_bfloat16* __restrict__ Hb_,
    const float* __restrict__ dec_b, float* __restrict__ out) {
  const int Nn = 512, K = 512;
  __shared__ __align__(16) short As[2][64 * 64];
  __shared__ __align__(16) short Bs[2][64 * 64];
  int p = blockIdx.x;  // 0..35
  int bb = blockIdx.y;
  int it = 0, rem = p;
  while (rem >= 8 - it) { rem -= 8 - it; ++it; }
  int jt = it + rem;
  const int row0 = it * 64, col0 = jt * 64;
  const int tid = threadIdx.x;
  const int lane = tid & 63, wave = tid >> 6;
  const int quad = lane >> 4, l15 = lane & 15;
  const int wr = (wave >> 1) * 32, wc = (wave & 1) * 32;
  const short* Ag = (const short*)(Tb_ + (size_t)bb * Nn * K);
  const short* Bg = (const short*)(Hb_ + (size_t)bb * Nn * K);

  auto stage = [&](int bsel, int k0) {
#pragma unroll
    for (int i = 0; i < 2; ++i) {
      int c = (wave * 2 + i) * 64 + lane;
      int r = c >> 3, pp = c & 7;
      int kc = pp ^ (r & 7);
      async16(&As[bsel][(wave * 2 + i) * 512], &Ag[(size_t)(row0 + r) * K + k0 + kc * 8]);
      async16(&Bs[bsel][(wave * 2 + i) * 512], &Bg[(size_t)(col0 + r) * K + k0 + kc * 8]);
    }
  };

  f32x4 acc[2][2] = {};
  const int nk = K >> 6;
  stage(0, 0);
  for (int t = 0; t < nk; ++t) {
    const int cur = t & 1;
    __syncthreads();
    if (t + 1 < nk) stage(cur ^ 1, (t + 1) << 6);
#pragma unroll
    for (int kh = 0; kh < 2; ++kh) {
      const int ch = ((quad + kh * 4) ^ (l15 & 7)) * 8;
      bf16x8 af[2], bq[2];
#pragma unroll
      for (int mi = 0; mi < 2; ++mi)
        af[mi] = *(const bf16x8*)&As[cur][(wr + mi * 16 + l15) * 64 + ch];
#pragma unroll
      for (int ni = 0; ni < 2; ++ni)
        bq[ni] = *(const bf16x8*)&Bs[cur][(wc + ni * 16 + l15) * 64 + ch];
#pragma unroll
      for (int mi = 0; mi < 2; ++mi)
#pragma unroll
        for (int ni = 0; ni < 2; ++ni)
          acc[mi][ni] = __builtin_amdgcn_mfma_f32_16x16x32_bf16(af[mi], bq[ni], acc[mi][ni], 0, 0, 0);
    }
  }

  float db = dec_b[0];
  size_t obase = (size_t)bb * ((size_t)Nn * (Nn - 1) / 2);
#pragma unroll
  for (int mi = 0; mi < 2; ++mi) {
#pragma unroll
    for (int ni = 0; ni < 2; ++ni) {
      int j = col0 + wc + ni * 16 + l15;
#pragma unroll
      for (int r = 0; r < 4; ++r) {
        int i = row0 + wr + mi * 16 + quad * 4 + r;
        if (j > i) {
          float x = acc[mi][ni][r] + db;
          float sp = fmaxf(x, 0.f) + __logf(1.f + __expf(-fabsf(x)));
          out[obase + (size_t)i * (2 * Nn - i - 1) / 2 + (j - i - 1)] = sp;
        }
      }
    }
  }
}

// ---------- LayerNorm: one wave per row (D=512), 4 rows/block, float4 loads ----------
__global__ __launch_bounds__(256) void ln_kernel(
    const float* __restrict__ X, float* __restrict__ outf,
    __hip_bfloat16* __restrict__ outb, const float* __restrict__ g,
    const float* __restrict__ b, int do_gelu) {
  const int row = blockIdx.x * 4 + (threadIdx.x >> 6);
  const int lane = threadIdx.x & 63;
  const float4* x = (const float4*)X + (size_t)row * 128;
  float4 v0 = x[lane], v1 = x[lane + 64];
  float s = v0.x + v0.y + v0.z + v0.w + v1.x + v1.y + v1.z + v1.w;
  float s2 = v0.x * v0.x + v0.y * v0.y + v0.z * v0.z + v0.w * v0.w +
             v1.x * v1.x + v1.y * v1.y + v1.z * v1.z + v1.w * v1.w;
#pragma unroll
  for (int off = 32; off; off >>= 1) {
    s += __shfl_xor(s, off, 64);
    s2 += __shfl_xor(s2, off, 64);
  }
  const float mean = s * (1.0f / 512.0f);
  const float inv = rsqrtf(s2 * (1.0f / 512.0f) - mean * mean + 1e-5f);
  const float4 g0 = ((const float4*)g)[lane], g1 = ((const float4*)g)[lane + 64];
  const float4 b0 = ((const float4*)b)[lane], b1 = ((const float4*)b)[lane + 64];
  float4 y0, y1;
  y0.x = (v0.x - mean) * inv * g0.x + b0.x;
  y0.y = (v0.y - mean) * inv * g0.y + b0.y;
  y0.z = (v0.z - mean) * inv * g0.z + b0.z;
  y0.w = (v0.w - mean) * inv * g0.w + b0.w;
  y1.x = (v1.x - mean) * inv * g1.x + b1.x;
  y1.y = (v1.y - mean) * inv * g1.y + b1.y;
  y1.z = (v1.z - mean) * inv * g1.z + b1.z;
  y1.w = (v1.w - mean) * inv * g1.w + b1.w;
  if (do_gelu) {
    y0.x = gelu_f(y0.x); y0.y = gelu_f(y0.y); y0.z = gelu_f(y0.z); y0.w = gelu_f(y0.w);
    y1.x = gelu_f(y1.x); y1.y = gelu_f(y1.y); y1.z = gelu_f(y1.z); y1.w = gelu_f(y1.w);
  }
  if (outf) {
    float4* of = (float4*)outf + (size_t)row * 128;
    of[lane] = y0;
    of[lane + 64] = y1;
  }
  if (outb) {
    s16x4 p0, p1;
    p0.x = bf16s(y0.x); p0.y = bf16s(y0.y); p0.z = bf16s(y0.z); p0.w = bf16s(y0.w);
    p1.x = bf16s(y1.x); p1.y = bf16s(y1.y); p1.z = bf16s(y1.z); p1.w = bf16s(y1.w);
    *(s16x4*)((short*)outb + (size_t)row * 512 + lane * 4) = p0;
    *(s16x4*)((short*)outb + (size_t)row * 512 + 256 + lane * 4) = p1;
  }
}

// ---------- batched transpose ----------
template <typename T>
__global__ __launch_bounds__(256) void transpose_kernel(
    const T* __restrict__ X, T* __restrict__ Y, int R, int C) {
  __shared__ T t[32][33];
  const T* xb = X + (size_t)blockIdx.z * R * C;
  T* yb = Y + (size_t)blockIdx.z * R * C;
  int c0 = blockIdx.x * 32, r0 = blockIdx.y * 32;
  int tx = threadIdx.x & 31, ty = threadIdx.x >> 5;
  for (int i = ty; i < 32; i += 8) t[i][tx] = xb[(size_t)(r0 + i) * C + c0 + tx];
  __syncthreads();
  for (int i = ty; i < 32; i += 8) yb[(size_t)(c0 + i) * R + r0 + tx] = t[tx][i];
}

// ---------- host ----------
extern "C" void kernel_launch(void* const* d_in, const int* in_sizes, int n_in,
                              void* d_out, int out_size, void* d_ws, size_t ws_size,
                              hipStream_t stream) {
  const float *A_lr = (const float*)d_in[0], *X_lr = (const float*)d_in[1],
              *ip_W = (const float*)d_in[2], *ip_b = (const float*)d_in[3],
              *ip_g = (const float*)d_in[4], *ip_bt = (const float*)d_in[5],
              *e_n1g = (const float*)d_in[6], *e_n1b = (const float*)d_in[7],
              *e_qkvW = (const float*)d_in[8], *e_qkvb = (const float*)d_in[9],
              *e_projW = (const float*)d_in[10], *e_projb = (const float*)d_in[11],
              *e_ebW = (const float*)d_in[12], *e_ebs = (const float*)d_in[13],
              *e_n2g = (const float*)d_in[14], *e_n2b = (const float*)d_in[15],
              *e_f1W = (const float*)d_in[16], *e_f1b = (const float*)d_in[17],
              *e_f2W = (const float*)d_in[18], *e_f2b = (const float*)d_in[19],
              *encn_g = (const float*)d_in[20], *encn_b = (const float*)d_in[21],
              *up1W = (const float*)d_in[22], *up1b = (const float*)d_in[23],
              *up2W = (const float*)d_in[24], *up2b = (const float*)d_in[25],
              *r_n1g = (const float*)d_in[26], *r_n1b = (const float*)d_in[27],
              *r_qkvW = (const float*)d_in[28], *r_qkvb = (const float*)d_in[29],
              *r_projW = (const float*)d_in[30], *r_projb = (const float*)d_in[31],
              *r_n2g = (const float*)d_in[32], *r_n2b = (const float*)d_in[33],
              *r_f1W = (const float*)d_in[34], *r_f1b = (const float*)d_in[35],
              *r_f2W = (const float*)d_in[36], *r_f2b = (const float*)d_in[37],
              *hrn_g = (const float*)d_in[38], *hrn_b = (const float*)d_in[39],
              *dec_W = (const float*)d_in[40], *dec_b = (const float*)d_in[41];

  const int Bb = 16, NLR = 256, NHR = 512, Dm = 512, NHh = 8, FF = 2048, Ll = 4;
  typedef __hip_bfloat16 bf;

  float* ws = (float*)d_ws;
  float* H = ws;                                  // 4M fp32
  float* Hf = ws + 4194304;                       // 4M fp32
  bf* XNb = (bf*)(ws + 8388608);                  // 4M bf16
  bf* AOb = (bf*)(ws + 10485760);                 // 4M bf16 (Htb / Ttb / attn out)
  bf* BIGb = (bf*)(ws + 12582912);                // 16.78M bf16 (QKV slab / FFN hidden)
  bf* WB = (bf*)(ws + 20971520);                  // bf16 weights
  bf* Xlrb = (bf*)(ws + 29229056);                // 1.05M bf16
  bf* Albrb = (bf*)(ws + 29753344);               // 1.05M bf16 (A_lr)

  size_t o = 0;
  bf* ipWt = WB + o;   o += (size_t)512 * 256;
  bf* eqkvT = WB + o;  o += (size_t)4 * 1536 * 512;
  bf* eprojT = WB + o; o += (size_t)4 * 512 * 512;
  bf* ef1T = WB + o;   o += (size_t)4 * 2048 * 512;
  bf* ef2T = WB + o;   o += (size_t)4 * 512 * 2048;
  bf* up1T = WB + o;   o += (size_t)512 * 256;
  bf* up2T = WB + o;   o += (size_t)512 * 512;
  bf* rqkvT = WB + o;  o += (size_t)1536 * 512;
  bf* rprojT = WB + o; o += (size_t)512 * 512;
  bf* rf1T = WB + o;   o += (size_t)2048 * 512;
  bf* rf2T = WB + o;   o += (size_t)512 * 2048;
  bf* Sb = WB + o;     o += (size_t)512 * 512;

  bf* Q_e = BIGb;
  bf* K_e = BIGb + 2097152;
  bf* V_e = BIGb + 4194304;
  bf* Q_r = BIGb;
  bf* K_r = BIGb + 4194304;
  bf* V_r = BIGb + 8388608;

  // ---- conversions (3 dispatches) ----
  CvArgs cv;
  cv.s[0] = ip_W;   cv.d[0] = ipWt;
  cv.s[1] = e_qkvW; cv.d[1] = eqkvT;
  cv.s[2] = e_projW; cv.d[2] = eprojT;
  cv.s[3] = e_f1W;  cv.d[3] = ef1T;
  cv.s[4] = e_f2W;  cv.d[4] = ef2T;
  cv.s[5] = up1W;   cv.d[5] = up1T;
  cv.s[6] = up2W;   cv.d[6] = up2T;
  cv.s[7] = r_qkvW; cv.d[7] = rqkvT;
  cv.s[8] = r_projW; cv.d[8] = rprojT;
  cv.s[9] = r_f1W;  cv.d[9] = rf1T;
  cv.s[10] = r_f2W; cv.d[10] = rf2T;
  multi_tconv_kernel<<<15872, 256, 0, stream>>>(cv);
  conv2_kernel<<<(1048576 + 255) / 256, 256, 0, stream>>>(
      X_lr, Xlrb, A_lr, Albrb, 1048576);
  build_s_kernel<<<(512 * 512 + 255) / 256, 256, 0, stream>>>(dec_W, Sb, Dm, 4);

  // ---- input projection ----  (M=4096: 64 m-tiles, mgrp=8; N=512: 8 n-tiles; K=256)
  mgemm64_kernel<<<512, 256, 0, stream>>>(
      Xlrb, ipWt, ip_b, nullptr, Hf, nullptr, Bb * NLR, Dm, NLR, 0, 8);
  ln_kernel<<<Bb * NLR / 4, 256, 0, stream>>>(Hf, H, nullptr, ip_g, ip_bt, 1);

  // ---- encoder ----  (M=4096)
  for (int l = 0; l < Ll; ++l) {
    ln_kernel<<<Bb * NLR / 4, 256, 0, stream>>>(H, nullptr, XNb, e_n1g + l * Dm, e_n1b + l * Dm, 0);
    qkv_gemm_kernel<<<768, 256, 0, stream>>>(
        XNb, eqkvT + (size_t)l * 1536 * 512, e_qkvb + l * 1536, BIGb,
        Bb * NLR, Dm, NLR, 8, 4);
    fattn_kernel<<<16 * 8 * 4, 256, 0, stream>>>(
        Q_e, K_e, V_e, AOb, Albrb, e_ebW + l * NHh, e_ebs + l, NLR, 2);
    mgemm64p_kernel<<<512, 256, 0, stream>>>(
        AOb, eprojT + (size_t)l * 512 * 512, e_projb + l * Dm, H,
        H, nullptr, Bb * NLR, Dm, Dm, 0, 8);
    ln_kernel<<<Bb * NLR / 4, 256, 0, stream>>>(H, nullptr, XNb, e_n2g + l * Dm, e_n2b + l * Dm, 0);
    mgemm_w8_kernel<<<512, 512, 0, stream>>>(
        XNb, ef1T + (size_t)l * 2048 * 512, e_f1b + l * FF, nullptr,
        nullptr, BIGb, Bb * NLR, FF, Dm, 1, 4);
    mgemm64p_kernel<<<512, 256, 0, stream>>>(
        BIGb, ef2T + (size_t)l * 512 * 2048, e_f2b + l * Dm, H,
        H, nullptr, Bb * NLR, Dm, FF, 0, 8);
  }

  // ---- upsampler ----  (M=8192)
  ln_kernel<<<Bb * NLR / 4, 256, 0, stream>>>(H, nullptr, XNb, encn_g, encn_b, 0);
  transpose_kernel<bf><<<dim3(16, 8, Bb), 256, 0, stream>>>(XNb, AOb, NLR, Dm);
  mgemm128_kernel<<<512, 256, 0, stream>>>(
      AOb, up1T, up1b, nullptr, nullptr, BIGb, Bb * Dm, NHR, NLR, 1, 8);
  mgemm64p_kernel<<<1024, 256, 0, stream>>>(
      BIGb, up2T, up2b, nullptr, Hf, nullptr, Bb * Dm, NHR, NHR, 0, 16);
  transpose_kernel<float><<<dim3(16, 16, Bb), 256, 0, stream>>>(Hf, H, Dm, NHR);

  // ---- refiner ----  (M=8192)
  ln_kernel<<<Bb * NHR / 4, 256, 0, stream>>>(H, nullptr, XNb, r_n1g, r_n1b, 0);
  qkv_gemm_kernel<<<1536, 256, 0, stream>>>(
      XNb, rqkvT, r_qkvb, BIGb, Bb * NHR, Dm, NHR, 9, 8);
  fattn_kernel<<<16 * 8 * 8, 256, 0, stream>>>(
      Q_r, K_r, V_r, AOb, nullptr, nullptr, nullptr, NHR, 3);
  mgemm64p_kernel<<<1024, 256, 0, stream>>>(
      AOb, rprojT, r_projb, H, H, nullptr, Bb * NHR, Dm, Dm, 0, 16);
  ln_kernel<<<Bb * NHR / 4, 256, 0, stream>>>(H, nullptr, XNb, r_n2g, r_n2b, 0);
  mgemm_w8_kernel<<<1024, 512, 0, stream>>>(
      XNb, rf1T, r_f1b, nullptr, nullptr, BIGb, Bb * NHR, FF, Dm, 1, 8);
  mgemm64p_kernel<<<1024, 256, 0, stream>>>(
      BIGb, rf2T, r_f2b, H, H, nullptr, Bb * NHR, Dm, FF, 0, 16);

  // ---- decoder ----
  ln_kernel<<<Bb * NHR / 4, 256, 0, stream>>>(H, nullptr, XNb, hrn_g, hrn_b, 0);
  mgemm64p_kernel<<<1024, 256, 0, stream>>>(
      XNb, Sb, nullptr, nullptr, nullptr, AOb, Bb * NHR, Dm, Dm, 0, 16);
  dec_mfma_kernel<<<dim3(36, Bb), 256, 0, stream>>>(
      AOb, XNb, dec_b, (float*)d_out);
}

// Round 11
// 792.699 us; speedup vs baseline: 1.0477x; 1.0477x over previous
//
#include <hip/hip_runtime.h>
#include <hip/hip_bf16.h>
#include <math.h>

#define DEV __device__ __forceinline__

typedef __attribute__((ext_vector_type(8))) short bf16x8;
typedef __attribute__((ext_vector_type(4))) short s16x4;
typedef __attribute__((ext_vector_type(4))) float f32x4;

// fast tanh-form GELU: x * sigmoid(1.5957691*x*(1+0.044715x^2))
DEV float gelu_f(float x) {
  float u = 1.5957691f * x * (1.0f + 0.044715f * x * x);
  return x / (1.0f + __expf(-u));
}

DEV short bf16s(float x) {
  __hip_bfloat16 v = __float2bfloat16(x);
  return *reinterpret_cast<short*>(&v);
}

// async 16B global->LDS (gfx950). dest = wave-uniform base + lane*16.
DEV void async16(void* lds, const void* g) {
  __builtin_amdgcn_global_load_lds(
      (const __attribute__((address_space(1))) unsigned int*)g,
      (__attribute__((address_space(3))) unsigned int*)lds, 16, 0, 0);
}

// ---------- fused conversions ----------
__global__ __launch_bounds__(256) void conv2_kernel(
    const float* __restrict__ X1, __hip_bfloat16* __restrict__ Y1,
    const float* __restrict__ X2, __hip_bfloat16* __restrict__ Y2, int n) {
  int i = blockIdx.x * 256 + threadIdx.x;
  if (i < n) {
    Y1[i] = __float2bfloat16(X1[i]);
    Y2[i] = __float2bfloat16(X2[i]);
  }
}

struct CvArgs {
  const float* s[11];
  __hip_bfloat16* d[11];
};

__global__ __launch_bounds__(256) void multi_tconv_kernel(CvArgs a) {
  const int Rj[11] = {256, 512, 512, 512, 2048, 256, 512, 512, 512, 512, 2048};
  const int Cj[11] = {512, 1536, 512, 2048, 512, 512, 512, 1536, 512, 2048, 512};
  const int Nj[11] = {1, 4, 4, 4, 4, 1, 1, 1, 1, 1, 1};
  __shared__ float t[32][33];
  int rem = blockIdx.x, j = 0;
  for (; j < 11; ++j) {
    int tj = (Rj[j] >> 5) * (Cj[j] >> 5) * Nj[j];
    if (rem < tj) break;
    rem -= tj;
  }
  const int R = Rj[j], C = Cj[j];
  const int perb = (R >> 5) * (C >> 5);
  const int z = rem / perb;
  const int tt = rem % perb;
  const int tc = C >> 5;
  const int r0 = (tt / tc) << 5, c0 = (tt % tc) << 5;
  const float* xb = a.s[j] + (size_t)z * R * C;
  __hip_bfloat16* yb = a.d[j] + (size_t)z * R * C;
  int tx = threadIdx.x & 31, ty = threadIdx.x >> 5;
  for (int i = ty; i < 32; i += 8) t[i][tx] = xb[(size_t)(r0 + i) * C + c0 + tx];
  __syncthreads();
  for (int i = ty; i < 32; i += 8)
    yb[(size_t)(c0 + i) * R + r0 + tx] = __float2bfloat16(t[tx][i]);
}

__global__ __launch_bounds__(256) void build_s_kernel(
    const float* __restrict__ W, __hip_bfloat16* __restrict__ S, int D, int Kk) {
  int i = blockIdx.x * 256 + threadIdx.x;
  if (i >= D * D) return;
  int d = i / D, e = i % D;
  float s = 0.f;
  for (int k = 0; k < Kk; ++k) {
    s += W[(size_t)k * D * D + i];
    s += W[(size_t)k * D * D + (size_t)e * D + d];
  }
  S[i] = __float2bfloat16(s / (2.0f * Kk));
}

// ---------- MFMA GEMM A: 64x64 tile, dbuf (32KB -> 4-5 blocks/CU). M=4096 N=512. ----------
__global__ __launch_bounds__(256) void mgemm64_kernel(
    const __hip_bfloat16* __restrict__ A, const __hip_bfloat16* __restrict__ Bt,
    const float* __restrict__ bias, const float* __restrict__ resid,
    float* __restrict__ outf, __hip_bfloat16* __restrict__ outb,
    int M, int N, int K, int act, int mgrp) {
  __shared__ __align__(16) short As[2][64 * 64];
  __shared__ __align__(16) short Bs[2][64 * 64];
  const int tid = threadIdx.x;
  const int lane = tid & 63, wave = tid >> 6;
  const int quad = lane >> 4, l15 = lane & 15;
  const int bid = blockIdx.x;
  const int g = bid & 7, sidx = bid >> 3;
  const int mt = g * mgrp + sidx % mgrp;
  const int nt = sidx / mgrp;
  const int row0 = mt * 64, col0 = nt * 64;
  const short* Ag = (const short*)A;
  const short* Bg = (const short*)Bt;

  auto stage = [&](int bsel, int k0) {
#pragma unroll
    for (int i = 0; i < 2; ++i) {
      int c = (wave * 2 + i) * 64 + lane;
      int r = c >> 3, pp = c & 7;
      int kc = pp ^ (r & 7);
      async16(&As[bsel][(wave * 2 + i) * 512], &Ag[(size_t)(row0 + r) * K + k0 + kc * 8]);
      async16(&Bs[bsel][(wave * 2 + i) * 512], &Bg[(size_t)(col0 + r) * K + k0 + kc * 8]);
    }
  };

  f32x4 acc[4] = {};
  const int nk = K >> 6;
  stage(0, 0);
  for (int t = 0; t < nk; ++t) {
    const int cur = t & 1;
    __syncthreads();  // drains loads for buf cur
    if (t + 1 < nk) stage(cur ^ 1, (t + 1) << 6);
#pragma unroll
    for (int kh = 0; kh < 2; ++kh) {
      const int ch = ((quad + kh * 4) ^ (l15 & 7)) * 8;
      bf16x8 af = *(const bf16x8*)&As[cur][(wave * 16 + l15) * 64 + ch];
#pragma unroll
      for (int ni = 0; ni < 4; ++ni) {
        bf16x8 bq = *(const bf16x8*)&Bs[cur][(ni * 16 + l15) * 64 + ch];
        acc[ni] = __builtin_amdgcn_mfma_f32_16x16x32_bf16(af, bq, acc[ni], 0, 0, 0);
      }
    }
  }

#pragma unroll
  for (int ni = 0; ni < 4; ++ni) {
    int cc = col0 + ni * 16 + l15;
    float bb = bias ? bias[cc] : 0.f;
#pragma unroll
    for (int r = 0; r < 4; ++r) {
      int rr = row0 + wave * 16 + quad * 4 + r;
      size_t idx = (size_t)rr * N + cc;
      float v = acc[ni][r] + bb;
      if (act) v = gelu_f(v);
      if (resid) v += resid[idx];
      if (outf) outf[idx] = v;
      if (outb) outb[idx] = __float2bfloat16(v);
    }
  }
}

// ---------- MFMA GEMM B: 128x64 tile, 4 waves, dbuf 48KB -> 3 blocks/CU.
// For M=8192 GEMMs (N=512 -> grid 512 = clean 2/CU). Ratio 1.33. ----------
__global__ __launch_bounds__(256) void mgemm128_kernel(
    const __hip_bfloat16* __restrict__ A, const __hip_bfloat16* __restrict__ Bt,
    const float* __restrict__ bias, const float* __restrict__ resid,
    float* __restrict__ outf, __hip_bfloat16* __restrict__ outb,
    int M, int N, int K, int act, int mgrp) {
  __shared__ __align__(16) short As[2][128 * 64];
  __shared__ __align__(16) short Bs[2][64 * 64];
  const int tid = threadIdx.x;
  const int lane = tid & 63, wave = tid >> 6;
  const int quad = lane >> 4, l15 = lane & 15;
  const int wr = wave >> 1, wc = wave & 1;  // 2x2 wave grid: 64 rows x 32 cols each
  const int bid = blockIdx.x;
  const int g = bid & 7, sidx = bid >> 3;
  const int mt = g * mgrp + sidx % mgrp;
  const int nt = sidx / mgrp;
  const int row0 = mt * 128, col0 = nt * 64;
  const short* Ag = (const short*)A;
  const short* Bg = (const short*)Bt;

  auto stage = [&](int bsel, int k0) {
#pragma unroll
    for (int i = 0; i < 4; ++i) {  // A: 128 rows x 64 cols = 1024 chunks
      int c = i * 256 + tid;
      int r = c >> 3, pp = c & 7;
      int kc = pp ^ (r & 7);
      async16(&As[bsel][c * 8], &Ag[(size_t)(row0 + r) * K + k0 + kc * 8]);
    }
#pragma unroll
    for (int i = 0; i < 2; ++i) {  // B: 64 rows x 64 cols = 512 chunks
      int c = i * 256 + tid;
      int r = c >> 3, pp = c & 7;
      int kc = pp ^ (r & 7);
      async16(&Bs[bsel][c * 8], &Bg[(size_t)(col0 + r) * K + k0 + kc * 8]);
    }
  };

  f32x4 acc[4][2] = {};
  const int nk = K >> 6;
  stage(0, 0);
  for (int t = 0; t < nk; ++t) {
    const int cur = t & 1;
    __syncthreads();
    if (t + 1 < nk) stage(cur ^ 1, (t + 1) << 6);
#pragma unroll
    for (int kh = 0; kh < 2; ++kh) {
      const int ch = ((quad + kh * 4) ^ (l15 & 7)) * 8;
      bf16x8 af[4], bq[2];
#pragma unroll
      for (int mi = 0; mi < 4; ++mi)
        af[mi] = *(const bf16x8*)&As[cur][(wr * 64 + mi * 16 + l15) * 64 + ch];
#pragma unroll
      for (int ni = 0; ni < 2; ++ni)
        bq[ni] = *(const bf16x8*)&Bs[cur][(wc * 32 + ni * 16 + l15) * 64 + ch];
#pragma unroll
      for (int mi = 0; mi < 4; ++mi)
#pragma unroll
        for (int ni = 0; ni < 2; ++ni)
          acc[mi][ni] = __builtin_amdgcn_mfma_f32_16x16x32_bf16(af[mi], bq[ni], acc[mi][ni], 0, 0, 0);
    }
  }

#pragma unroll
  for (int ni = 0; ni < 2; ++ni) {
    int cc = col0 + wc * 32 + ni * 16 + l15;
    float bb = bias ? bias[cc] : 0.f;
#pragma unroll
    for (int mi = 0; mi < 4; ++mi) {
#pragma unroll
      for (int r = 0; r < 4; ++r) {
        int rr = row0 + wr * 64 + mi * 16 + quad * 4 + r;
        size_t idx = (size_t)rr * N + cc;
        float v = acc[mi][ni][r] + bb;
        if (act) v = gelu_f(v);
        if (resid) v += resid[idx];
        if (outf) outf[idx] = v;
        if (outb) outb[idx] = __float2bfloat16(v);
      }
    }
  }
}

// ---------- MFMA GEMM C: 128x128 tile, 8 WAVES (512 thr), dbuf 64KB -> 2 blocks/CU.
// For FFN1 (N=2048: clean 512/1024 grids). Per-wave 64x32: 16 MFMA : 12 ds_read. ----------
__global__ __launch_bounds__(512) void mgemm_w8_kernel(
    const __hip_bfloat16* __restrict__ A, const __hip_bfloat16* __restrict__ Bt,
    const float* __restrict__ bias, const float* __restrict__ resid,
    float* __restrict__ outf, __hip_bfloat16* __restrict__ outb,
    int M, int N, int K, int act, int mgrp) {
  __shared__ __align__(16) short As[2][128 * 64];
  __shared__ __align__(16) short Bs[2][128 * 64];
  const int tid = threadIdx.x;
  const int lane = tid & 63, wave = tid >> 6;
  const int quad = lane >> 4, l15 = lane & 15;
  const int wr = wave >> 2, wc = wave & 3;  // 2x4 wave grid: 64 rows x 32 cols each
  const int bid = blockIdx.x;
  const int g = bid & 7, sidx = bid >> 3;
  const int mt = g * mgrp + sidx % mgrp;
  const int nt = sidx / mgrp;
  const int row0 = mt * 128, col0 = nt * 128;
  const short* Ag = (const short*)A;
  const short* Bg = (const short*)Bt;

  auto stage = [&](int bsel, int k0) {
#pragma unroll
    for (int i = 0; i < 2; ++i) {  // A: 128x64 = 1024 chunks over 512 threads
      int c = i * 512 + tid;
      int r = c >> 3, pp = c & 7;
      int kc = pp ^ (r & 7);
      async16(&As[bsel][c * 8], &Ag[(size_t)(row0 + r) * K + k0 + kc * 8]);
    }
#pragma unroll
    for (int i = 0; i < 2; ++i) {  // B: 128x64 = 1024 chunks
      int c = i * 512 + tid;
      int r = c >> 3, pp = c & 7;
      int kc = pp ^ (r & 7);
      async16(&Bs[bsel][c * 8], &Bg[(size_t)(col0 + r) * K + k0 + kc * 8]);
    }
  };

  f32x4 acc[4][2] = {};
  const int nk = K >> 6;
  stage(0, 0);
  for (int t = 0; t < nk; ++t) {
    const int cur = t & 1;
    __syncthreads();
    if (t + 1 < nk) stage(cur ^ 1, (t + 1) << 6);
#pragma unroll
    for (int kh = 0; kh < 2; ++kh) {
      const int ch = ((quad + kh * 4) ^ (l15 & 7)) * 8;
      bf16x8 af[4], bq[2];
#pragma unroll
      for (int mi = 0; mi < 4; ++mi)
        af[mi] = *(const bf16x8*)&As[cur][(wr * 64 + mi * 16 + l15) * 64 + ch];
#pragma unroll
      for (int ni = 0; ni < 2; ++ni)
        bq[ni] = *(const bf16x8*)&Bs[cur][(wc * 32 + ni * 16 + l15) * 64 + ch];
#pragma unroll
      for (int mi = 0; mi < 4; ++mi)
#pragma unroll
        for (int ni = 0; ni < 2; ++ni)
          acc[mi][ni] = __builtin_amdgcn_mfma_f32_16x16x32_bf16(af[mi], bq[ni], acc[mi][ni], 0, 0, 0);
    }
  }

#pragma unroll
  for (int ni = 0; ni < 2; ++ni) {
    int cc = col0 + wc * 32 + ni * 16 + l15;
    float bb = bias ? bias[cc] : 0.f;
#pragma unroll
    for (int mi = 0; mi < 4; ++mi) {
#pragma unroll
      for (int r = 0; r < 4; ++r) {
        int rr = row0 + wr * 64 + mi * 16 + quad * 4 + r;
        size_t idx = (size_t)rr * N + cc;
        float v = acc[mi][ni][r] + bb;
        if (act) v = gelu_f(v);
        if (resid) v += resid[idx];
        if (outf) outf[idx] = v;
        if (outb) outb[idx] = __float2bfloat16(v);
      }
    }
  }
}

// ---------- QKV GEMM (128x64 tile, 4 waves, dbuf 48KB -> 3 blk/CU; clean grids
// 768 (encoder) / 1536 (refiner)) with head-layout scatter ----------
__global__ __launch_bounds__(256) void qkv_gemm_kernel(
    const __hip_bfloat16* __restrict__ A, const __hip_bfloat16* __restrict__ Bt,
    const float* __restrict__ bias, __hip_bfloat16* __restrict__ qkv,
    int M, int K, int nseq, int lgn, int mgrp) {
  __shared__ __align__(16) short As[2][128 * 64];
  __shared__ __align__(16) short Bs[2][64 * 64];
  const int tid = threadIdx.x;
  const int lane = tid & 63, wave = tid >> 6;
  const int quad = lane >> 4, l15 = lane & 15;
  const int wr = wave >> 1, wc = wave & 1;
  const int bid = blockIdx.x;
  const int g = bid & 7, sidx = bid >> 3;
  const int mt = g * mgrp + sidx % mgrp;
  const int nt = sidx / mgrp;
  const int row0 = mt * 128, col0 = nt * 64;
  const short* Ag = (const short*)A;
  const short* Bg = (const short*)Bt;

  auto stage = [&](int bsel, int k0) {
#pragma unroll
    for (int i = 0; i < 4; ++i) {
      int c = i * 256 + tid;
      int r = c >> 3, pp = c & 7;
      int kc = pp ^ (r & 7);
      async16(&As[bsel][c * 8], &Ag[(size_t)(row0 + r) * K + k0 + kc * 8]);
    }
#pragma unroll
    for (int i = 0; i < 2; ++i) {
      int c = i * 256 + tid;
      int r = c >> 3, pp = c & 7;
      int kc = pp ^ (r & 7);
      async16(&Bs[bsel][c * 8], &Bg[(size_t)(col0 + r) * K + k0 + kc * 8]);
    }
  };

  f32x4 acc[4][2] = {};
  const int nk = K >> 6;
  stage(0, 0);
  for (int t = 0; t < nk; ++t) {
    const int cur = t & 1;
    __syncthreads();
    if (t + 1 < nk) stage(cur ^ 1, (t + 1) << 6);
#pragma unroll
    for (int kh = 0; kh < 2; ++kh) {
      const int ch = ((quad + kh * 4) ^ (l15 & 7)) * 8;
      bf16x8 af[4], bq[2];
#pragma unroll
      for (int mi = 0; mi < 4; ++mi)
        af[mi] = *(const bf16x8*)&As[cur][(wr * 64 + mi * 16 + l15) * 64 + ch];
#pragma unroll
      for (int ni = 0; ni < 2; ++ni)
        bq[ni] = *(const bf16x8*)&Bs[cur][(wc * 32 + ni * 16 + l15) * 64 + ch];
#pragma unroll
      for (int mi = 0; mi < 4; ++mi)
#pragma unroll
        for (int ni = 0; ni < 2; ++ni)
          acc[mi][ni] = __builtin_amdgcn_mfma_f32_16x16x32_bf16(af[mi], bq[ni], acc[mi][ni], 0, 0, 0);
    }
  }

  const size_t PART = (size_t)M * 512;
#pragma unroll
  for (int ni = 0; ni < 2; ++ni) {
    int cc = col0 + wc * 32 + ni * 16 + l15;  // 0..1535
    float bb = bias ? bias[cc] : 0.f;
    int which = cc >> 9;
    int h = (cc >> 6) & 7;
    int d = cc & 63;
#pragma unroll
    for (int mi = 0; mi < 4; ++mi) {
#pragma unroll
      for (int r = 0; r < 4; ++r) {
        int rr = row0 + wr * 64 + mi * 16 + quad * 4 + r;
        int b = rr >> lgn;
        int nn = rr & (nseq - 1);
        float v = acc[mi][ni][r] + bb;
        size_t dst;
        if (which == 2) {
          dst = 2 * PART + (((size_t)b * 8 + h) * 64 + d) * nseq + nn;
        } else {
          dst = (size_t)which * PART + (((size_t)b * 8 + h) * nseq + nn) * 64 + d;
        }
        qkv[dst] = __float2bfloat16(v);
      }
    }
  }
}

// ---------- fused flash attention (MFMA, NO-MAX softmax, dbuf, XCD-local) ----------
__global__ __launch_bounds__(256) void fattn_kernel(
    const __hip_bfloat16* __restrict__ Qh, const __hip_bfloat16* __restrict__ Kh,
    const __hip_bfloat16* __restrict__ Vt, __hip_bfloat16* __restrict__ O,
    const __hip_bfloat16* __restrict__ Abias, const float* __restrict__ ebW,
    const float* __restrict__ ebs, int N, int lgq) {
  __shared__ __align__(16) short Ks[2][64 * 64];
  __shared__ __align__(16) short Vs[2][64 * 64];
  __shared__ __align__(16) short Ps[4][16][72];
  const int bid = blockIdx.x;
  const int g = bid & 7, s = bid >> 3;
  const int bloc = s >> (lgq + 3);
  const int rem = s & ((8 << lgq) - 1);
  const int h = rem >> lgq;
  const int qt = rem & ((1 << lgq) - 1);
  const int b = g * 2 + bloc;
  const int tid = threadIdx.x, lane = tid & 63, wave = tid >> 6;
  const int quad = lane >> 4, l15 = lane & 15;
  const size_t hb = (size_t)b * 8 + h;
  const short* Qg = (const short*)Qh + hb * N * 64;
  const short* Kg = (const short*)Kh + hb * N * 64;
  const short* Vg = (const short*)Vt + hb * 64 * N;
  const float scale = 0.125f;
  const bool hasb = (Abias != nullptr);
  const float bscale = hasb ? ebs[0] * ebW[h] : 0.f;
  const int qrow_w = qt * 64 + wave * 16;

  auto stageKV = [&](int bsel, int k0) {
#pragma unroll
    for (int i = 0; i < 2; ++i) {
      int c = (wave * 2 + i) * 64 + lane;
      int r = c >> 3, pp = c & 7;
      int kc = pp ^ (r & 7);
      async16(&Ks[bsel][(wave * 2 + i) * 512], &Kg[(size_t)(k0 + r) * 64 + kc * 8]);
      async16(&Vs[bsel][(wave * 2 + i) * 512], &Vg[(size_t)r * N + k0 + kc * 8]);
    }
  };

  bf16x8 qf[2];
  qf[0] = *(const bf16x8*)&Qg[(size_t)(qrow_w + l15) * 64 + quad * 8];
  qf[1] = *(const bf16x8*)&Qg[(size_t)(qrow_w + l15) * 64 + quad * 8 + 32];

  float l_r[4] = {0.f, 0.f, 0.f, 0.f};
  f32x4 oacc[4] = {};

  const int ntl = N >> 6;
  stageKV(0, 0);
  for (int t = 0; t < ntl; ++t) {
    const int cur = t & 1;
    const int k0 = t << 6;
    __syncthreads();
    if (t + 1 < ntl) stageKV(cur ^ 1, (t + 1) << 6);

    f32x4 sv[4] = {};
    __builtin_amdgcn_s_setprio(1);
#pragma unroll
    for (int kh = 0; kh < 2; ++kh) {
      const int ch = ((quad + kh * 4) ^ (l15 & 7)) * 8;
#pragma unroll
      for (int ni = 0; ni < 4; ++ni) {
        bf16x8 kf = *(const bf16x8*)&Ks[cur][(ni * 16 + l15) * 64 + ch];
        sv[ni] = __builtin_amdgcn_mfma_f32_16x16x32_bf16(qf[kh], kf, sv[ni], 0, 0, 0);
      }
    }
    __builtin_amdgcn_s_setprio(0);
    if (hasb) {
#pragma unroll
      for (int ni = 0; ni < 4; ++ni)
#pragma unroll
        for (int r = 0; r < 4; ++r) {
          int qq = qrow_w + quad * 4 + r;
          int kk = k0 + ni * 16 + l15;
          float ab = __bfloat162float(Abias[((size_t)b * N + qq) * N + kk]);
          sv[ni][r] = sv[ni][r] * scale + bscale * ab;
        }
    } else {
#pragma unroll
      for (int ni = 0; ni < 4; ++ni)
#pragma unroll
        for (int r = 0; r < 4; ++r) sv[ni][r] *= scale;
    }

    // no-max softmax numerator: p = exp(s); accumulate local row sums
#pragma unroll
    for (int ni = 0; ni < 4; ++ni)
#pragma unroll
      for (int r = 0; r < 4; ++r) {
        float p = __expf(sv[ni][r]);
        sv[ni][r] = p;
        l_r[r] += p;
      }

#pragma unroll
    for (int ni = 0; ni < 4; ++ni)
#pragma unroll
      for (int r = 0; r < 4; ++r)
        Ps[wave][quad * 4 + r][ni * 16 + l15] = bf16s(sv[ni][r]);

    bf16x8 pf0 = *(const bf16x8*)&Ps[wave][l15][quad * 8];
    bf16x8 pf1 = *(const bf16x8*)&Ps[wave][l15][quad * 8 + 32];
    __builtin_amdgcn_s_setprio(1);
#pragma unroll
    for (int kh = 0; kh < 2; ++kh) {
      const int ch = ((quad + kh * 4) ^ (l15 & 7)) * 8;
#pragma unroll
      for (int ni = 0; ni < 4; ++ni) {
        bf16x8 vf = *(const bf16x8*)&Vs[cur][(ni * 16 + l15) * 64 + ch];
        oacc[ni] = __builtin_amdgcn_mfma_f32_16x16x32_bf16(kh ? pf1 : pf0, vf, oacc[ni], 0, 0, 0);
      }
    }
    __builtin_amdgcn_s_setprio(0);
  }

  // reduce row sums across the 16-lane row group, then normalize
#pragma unroll
  for (int off = 1; off < 16; off <<= 1)
#pragma unroll
    for (int r = 0; r < 4; ++r) l_r[r] += __shfl_xor(l_r[r], off, 64);
  float inv[4];
#pragma unroll
  for (int r = 0; r < 4; ++r) inv[r] = 1.f / l_r[r];
#pragma unroll
  for (int ni = 0; ni < 4; ++ni)
#pragma unroll
    for (int r = 0; r < 4; ++r) {
      int nn = qrow_w + quad * 4 + r;
      int col = h * 64 + ni * 16 + l15;
      O[((size_t)b * N + nn) * 512 + col] = __float2bfloat16(oacc[ni][r] * inv[r]);
    }
}

// ---------- decoder: 64x64 tiles (dbuf), 36 triu pairs x 16 batches ----------
__global__ __launch_bounds__(256) void dec_mfma_kernel(
    const __hip_bfloat16* __restrict__ Tb_, const __hip_bfloat16* __restrict__ Hb_,
    const float* __restrict__ dec_b, float* __restrict__ out) {
  const int Nn = 512, K = 512;
  __shared__ __align__(16) short As[2][64 * 64];
  __shared__ __align__(16) short Bs[2][64 * 64];
  int p = blockIdx.x;  // 0..35
  int bb = blockIdx.y;
  int it = 0, rem = p;
  while (rem >= 8 - it) { rem -= 8 - it; ++it; }
  int jt = it + rem;
  const int row0 = it * 64, col0 = jt * 64;
  const int tid = threadIdx.x;
  const int lane = tid & 63, wave = tid >> 6;
  const int quad = lane >> 4, l15 = lane & 15;
  const int wr = (wave >> 1) * 32, wc = (wave & 1) * 32;
  const short* Ag = (const short*)(Tb_ + (size_t)bb * Nn * K);
  const short* Bg = (const short*)(Hb_ + (size_t)bb * Nn * K);

  auto stage = [&](int bsel, int k0) {
#pragma unroll
    for (int i = 0; i < 2; ++i) {
      int c = (wave * 2 + i) * 64 + lane;
      int r = c >> 3, pp = c & 7;
      int kc = pp ^ (r & 7);
      async16(&As[bsel][(wave * 2 + i) * 512], &Ag[(size_t)(row0 + r) * K + k0 + kc * 8]);
      async16(&Bs[bsel][(wave * 2 + i) * 512], &Bg[(size_t)(col0 + r) * K + k0 + kc * 8]);
    }
  };

  f32x4 acc[2][2] = {};
  const int nk = K >> 6;
  stage(0, 0);
  for (int t = 0; t < nk; ++t) {
    const int cur = t & 1;
    __syncthreads();
    if (t + 1 < nk) stage(cur ^ 1, (t + 1) << 6);
#pragma unroll
    for (int kh = 0; kh < 2; ++kh) {
      const int ch = ((quad + kh * 4) ^ (l15 & 7)) * 8;
      bf16x8 af[2], bq[2];
#pragma unroll
      for (int mi = 0; mi < 2; ++mi)
        af[mi] = *(const bf16x8*)&As[cur][(wr + mi * 16 + l15) * 64 + ch];
#pragma unroll
      for (int ni = 0; ni < 2; ++ni)
        bq[ni] = *(const bf16x8*)&Bs[cur][(wc + ni * 16 + l15) * 64 + ch];
#pragma unroll
      for (int mi = 0; mi < 2; ++mi)
#pragma unroll
        for (int ni = 0; ni < 2; ++ni)
          acc[mi][ni] = __builtin_amdgcn_mfma_f32_16x16x32_bf16(af[mi], bq[ni], acc[mi][ni], 0, 0, 0);
    }
  }

  float db = dec_b[0];
  size_t obase = (size_t)bb * ((size_t)Nn * (Nn - 1) / 2);
#pragma unroll
  for (int mi = 0; mi < 2; ++mi) {
#pragma unroll
    for (int ni = 0; ni < 2; ++ni) {
      int j = col0 + wc + ni * 16 + l15;
#pragma unroll
      for (int r = 0; r < 4; ++r) {
        int i = row0 + wr + mi * 16 + quad * 4 + r;
        if (j > i) {
          float x = acc[mi][ni][r] + db;
          float sp = fmaxf(x, 0.f) + __logf(1.f + __expf(-fabsf(x)));
          out[obase + (size_t)i * (2 * Nn - i - 1) / 2 + (j - i - 1)] = sp;
        }
      }
    }
  }
}

// ---------- LayerNorm: one wave per row (D=512), 4 rows/block, float4 loads ----------
__global__ __launch_bounds__(256) void ln_kernel(
    const float* __restrict__ X, float* __restrict__ outf,
    __hip_bfloat16* __restrict__ outb, const float* __restrict__ g,
    const float* __restrict__ b, int do_gelu) {
  const int row = blockIdx.x * 4 + (threadIdx.x >> 6);
  const int lane = threadIdx.x & 63;
  const float4* x = (const float4*)X + (size_t)row * 128;
  float4 v0 = x[lane], v1 = x[lane + 64];
  float s = v0.x + v0.y + v0.z + v0.w + v1.x + v1.y + v1.z + v1.w;
  float s2 = v0.x * v0.x + v0.y * v0.y + v0.z * v0.z + v0.w * v0.w +
             v1.x * v1.x + v1.y * v1.y + v1.z * v1.z + v1.w * v1.w;
#pragma unroll
  for (int off = 32; off; off >>= 1) {
    s += __shfl_xor(s, off, 64);
    s2 += __shfl_xor(s2, off, 64);
  }
  const float mean = s * (1.0f / 512.0f);
  const float inv = rsqrtf(s2 * (1.0f / 512.0f) - mean * mean + 1e-5f);
  const float4 g0 = ((const float4*)g)[lane], g1 = ((const float4*)g)[lane + 64];
  const float4 b0 = ((const float4*)b)[lane], b1 = ((const float4*)b)[lane + 64];
  float4 y0, y1;
  y0.x = (v0.x - mean) * inv * g0.x + b0.x;
  y0.y = (v0.y - mean) * inv * g0.y + b0.y;
  y0.z = (v0.z - mean) * inv * g0.z + b0.z;
  y0.w = (v0.w - mean) * inv * g0.w + b0.w;
  y1.x = (v1.x - mean) * inv * g1.x + b1.x;
  y1.y = (v1.y - mean) * inv * g1.y + b1.y;
  y1.z = (v1.z - mean) * inv * g1.z + b1.z;
  y1.w = (v1.w - mean) * inv * g1.w + b1.w;
  if (do_gelu) {
    y0.x = gelu_f(y0.x); y0.y = gelu_f(y0.y); y0.z = gelu_f(y0.z); y0.w = gelu_f(y0.w);
    y1.x = gelu_f(y1.x); y1.y = gelu_f(y1.y); y1.z = gelu_f(y1.z); y1.w = gelu_f(y1.w);
  }
  if (outf) {
    float4* of = (float4*)outf + (size_t)row * 128;
    of[lane] = y0;
    of[lane + 64] = y1;
  }
  if (outb) {
    s16x4 p0, p1;
    p0.x = bf16s(y0.x); p0.y = bf16s(y0.y); p0.z = bf16s(y0.z); p0.w = bf16s(y0.w);
    p1.x = bf16s(y1.x); p1.y = bf16s(y1.y); p1.z = bf16s(y1.z); p1.w = bf16s(y1.w);
    *(s16x4*)((short*)outb + (size_t)row * 512 + lane * 4) = p0;
    *(s16x4*)((short*)outb + (size_t)row * 512 + 256 + lane * 4) = p1;
  }
}

// ---------- batched transpose ----------
template <typename T>
__global__ __launch_bounds__(256) void transpose_kernel(
    const T* __restrict__ X, T* __restrict__ Y, int R, int C) {
  __shared__ T t[32][33];
  const T* xb = X + (size_t)blockIdx.z * R * C;
  T* yb = Y + (size_t)blockIdx.z * R * C;
  int c0 = blockIdx.x * 32, r0 = blockIdx.y * 32;
  int tx = threadIdx.x & 31, ty = threadIdx.x >> 5;
  for (int i = ty; i < 32; i += 8) t[i][tx] = xb[(size_t)(r0 + i) * C + c0 + tx];
  __syncthreads();
  for (int i = ty; i < 32; i += 8) yb[(size_t)(c0 + i) * R + r0 + tx] = t[tx][i];
}

// ---------- host ----------
extern "C" void kernel_launch(void* const* d_in, const int* in_sizes, int n_in,
                              void* d_out, int out_size, void* d_ws, size_t ws_size,
                              hipStream_t stream) {
  const float *A_lr = (const float*)d_in[0], *X_lr = (const float*)d_in[1],
              *ip_W = (const float*)d_in[2], *ip_b = (const float*)d_in[3],
              *ip_g = (const float*)d_in[4], *ip_bt = (const float*)d_in[5],
              *e_n1g = (const float*)d_in[6], *e_n1b = (const float*)d_in[7],
              *e_qkvW = (const float*)d_in[8], *e_qkvb = (const float*)d_in[9],
              *e_projW = (const float*)d_in[10], *e_projb = (const float*)d_in[11],
              *e_ebW = (const float*)d_in[12], *e_ebs = (const float*)d_in[13],
              *e_n2g = (const float*)d_in[14], *e_n2b = (const float*)d_in[15],
              *e_f1W = (const float*)d_in[16], *e_f1b = (const float*)d_in[17],
              *e_f2W = (const float*)d_in[18], *e_f2b = (const float*)d_in[19],
              *encn_g = (const float*)d_in[20], *encn_b = (const float*)d_in[21],
              *up1W = (const float*)d_in[22], *up1b = (const float*)d_in[23],
              *up2W = (const float*)d_in[24], *up2b = (const float*)d_in[25],
              *r_n1g = (const float*)d_in[26], *r_n1b = (const float*)d_in[27],
              *r_qkvW = (const float*)d_in[28], *r_qkvb = (const float*)d_in[29],
              *r_projW = (const float*)d_in[30], *r_projb = (const float*)d_in[31],
              *r_n2g = (const float*)d_in[32], *r_n2b = (const float*)d_in[33],
              *r_f1W = (const float*)d_in[34], *r_f1b = (const float*)d_in[35],
              *r_f2W = (const float*)d_in[36], *r_f2b = (const float*)d_in[37],
              *hrn_g = (const float*)d_in[38], *hrn_b = (const float*)d_in[39],
              *dec_W = (const float*)d_in[40], *dec_b = (const float*)d_in[41];

  const int Bb = 16, NLR = 256, NHR = 512, Dm = 512, NHh = 8, FF = 2048, Ll = 4;
  typedef __hip_bfloat16 bf;

  float* ws = (float*)d_ws;
  float* H = ws;                                  // 4M fp32
  float* Hf = ws + 4194304;                       // 4M fp32
  bf* XNb = (bf*)(ws + 8388608);                  // 4M bf16
  bf* AOb = (bf*)(ws + 10485760);                 // 4M bf16 (Htb / Ttb / attn out)
  bf* BIGb = (bf*)(ws + 12582912);                // 16.78M bf16 (QKV slab / FFN hidden)
  bf* WB = (bf*)(ws + 20971520);                  // bf16 weights
  bf* Xlrb = (bf*)(ws + 29229056);                // 1.05M bf16
  bf* Albrb = (bf*)(ws + 29753344);               // 1.05M bf16 (A_lr)

  size_t o = 0;
  bf* ipWt = WB + o;   o += (size_t)512 * 256;
  bf* eqkvT = WB + o;  o += (size_t)4 * 1536 * 512;
  bf* eprojT = WB + o; o += (size_t)4 * 512 * 512;
  bf* ef1T = WB + o;   o += (size_t)4 * 2048 * 512;
  bf* ef2T = WB + o;   o += (size_t)4 * 512 * 2048;
  bf* up1T = WB + o;   o += (size_t)512 * 256;
  bf* up2T = WB + o;   o += (size_t)512 * 512;
  bf* rqkvT = WB + o;  o += (size_t)1536 * 512;
  bf* rprojT = WB + o; o += (size_t)512 * 512;
  bf* rf1T = WB + o;   o += (size_t)2048 * 512;
  bf* rf2T = WB + o;   o += (size_t)512 * 2048;
  bf* Sb = WB + o;     o += (size_t)512 * 512;

  bf* Q_e = BIGb;
  bf* K_e = BIGb + 2097152;
  bf* V_e = BIGb + 4194304;
  bf* Q_r = BIGb;
  bf* K_r = BIGb + 4194304;
  bf* V_r = BIGb + 8388608;

  // ---- conversions (3 dispatches) ----
  CvArgs cv;
  cv.s[0] = ip_W;   cv.d[0] = ipWt;
  cv.s[1] = e_qkvW; cv.d[1] = eqkvT;
  cv.s[2] = e_projW; cv.d[2] = eprojT;
  cv.s[3] = e_f1W;  cv.d[3] = ef1T;
  cv.s[4] = e_f2W;  cv.d[4] = ef2T;
  cv.s[5] = up1W;   cv.d[5] = up1T;
  cv.s[6] = up2W;   cv.d[6] = up2T;
  cv.s[7] = r_qkvW; cv.d[7] = rqkvT;
  cv.s[8] = r_projW; cv.d[8] = rprojT;
  cv.s[9] = r_f1W;  cv.d[9] = rf1T;
  cv.s[10] = r_f2W; cv.d[10] = rf2T;
  multi_tconv_kernel<<<15872, 256, 0, stream>>>(cv);
  conv2_kernel<<<(1048576 + 255) / 256, 256, 0, stream>>>(
      X_lr, Xlrb, A_lr, Albrb, 1048576);
  build_s_kernel<<<(512 * 512 + 255) / 256, 256, 0, stream>>>(dec_W, Sb, Dm, 4);

  // ---- input projection ----  (M=4096: 64 m-tiles, mgrp=8; N=512: 8 n-tiles)
  mgemm64_kernel<<<512, 256, 0, stream>>>(
      Xlrb, ipWt, ip_b, nullptr, Hf, nullptr, Bb * NLR, Dm, NLR, 0, 8);
  ln_kernel<<<Bb * NLR / 4, 256, 0, stream>>>(Hf, H, nullptr, ip_g, ip_bt, 1);

  // ---- encoder ----  (M=4096)
  for (int l = 0; l < Ll; ++l) {
    ln_kernel<<<Bb * NLR / 4, 256, 0, stream>>>(H, nullptr, XNb, e_n1g + l * Dm, e_n1b + l * Dm, 0);
    qkv_gemm_kernel<<<768, 256, 0, stream>>>(
        XNb, eqkvT + (size_t)l * 1536 * 512, e_qkvb + l * 1536, BIGb,
        Bb * NLR, Dm, NLR, 8, 4);
    fattn_kernel<<<16 * 8 * 4, 256, 0, stream>>>(
        Q_e, K_e, V_e, AOb, Albrb, e_ebW + l * NHh, e_ebs + l, NLR, 2);
    mgemm64_kernel<<<512, 256, 0, stream>>>(
        AOb, eprojT + (size_t)l * 512 * 512, e_projb + l * Dm, H,
        H, nullptr, Bb * NLR, Dm, Dm, 0, 8);
    ln_kernel<<<Bb * NLR / 4, 256, 0, stream>>>(H, nullptr, XNb, e_n2g + l * Dm, e_n2b + l * Dm, 0);
    mgemm_w8_kernel<<<512, 512, 0, stream>>>(
        XNb, ef1T + (size_t)l * 2048 * 512, e_f1b + l * FF, nullptr,
        nullptr, BIGb, Bb * NLR, FF, Dm, 1, 4);
    mgemm64_kernel<<<512, 256, 0, stream>>>(
        BIGb, ef2T + (size_t)l * 512 * 2048, e_f2b + l * Dm, H,
        H, nullptr, Bb * NLR, Dm, FF, 0, 8);
  }

  // ---- upsampler ----  (M=8192: 64 128-tiles, mgrp=8)
  ln_kernel<<<Bb * NLR / 4, 256, 0, stream>>>(H, nullptr, XNb, encn_g, encn_b, 0);
  transpose_kernel<bf><<<dim3(16, 8, Bb), 256, 0, stream>>>(XNb, AOb, NLR, Dm);
  mgemm128_kernel<<<512, 256, 0, stream>>>(
      AOb, up1T, up1b, nullptr, nullptr, BIGb, Bb * Dm, NHR, NLR, 1, 8);
  mgemm128_kernel<<<512, 256, 0, stream>>>(
      BIGb, up2T, up2b, nullptr, Hf, nullptr, Bb * Dm, NHR, NHR, 0, 8);
  transpose_kernel<float><<<dim3(16, 16, Bb), 256, 0, stream>>>(Hf, H, Dm, NHR);

  // ---- refiner ----  (M=8192: 64 128-tiles, mgrp=8)
  ln_kernel<<<Bb * NHR / 4, 256, 0, stream>>>(H, nullptr, XNb, r_n1g, r_n1b, 0);
  qkv_gemm_kernel<<<1536, 256, 0, stream>>>(
      XNb, rqkvT, r_qkvb, BIGb, Bb * NHR, Dm, NHR, 9, 8);
  fattn_kernel<<<16 * 8 * 8, 256, 0, stream>>>(
      Q_r, K_r, V_r, AOb, nullptr, nullptr, nullptr, NHR, 3);
  mgemm128_kernel<<<512, 256, 0, stream>>>(
      AOb, rprojT, r_projb, H, H, nullptr, Bb * NHR, Dm, Dm, 0, 8);
  ln_kernel<<<Bb * NHR / 4, 256, 0, stream>>>(H, nullptr, XNb, r_n2g, r_n2b, 0);
  mgemm_w8_kernel<<<1024, 512, 0, stream>>>(
      XNb, rf1T, r_f1b, nullptr, nullptr, BIGb, Bb * NHR, FF, Dm, 1, 8);
  mgemm128_kernel<<<512, 256, 0, stream>>>(
      BIGb, rf2T, r_f2b, H, H, nullptr, Bb * NHR, Dm, FF, 0, 8);

  // ---- decoder ----
  ln_kernel<<<Bb * NHR / 4, 256, 0, stream>>>(H, nullptr, XNb, hrn_g, hrn_b, 0);
  mgemm128_kernel<<<512, 256, 0, stream>>>(
      XNb, Sb, nullptr, nullptr, nullptr, AOb, Bb * NHR, Dm, Dm, 0, 8);
  dec_mfma_kernel<<<dim3(36, Bb), 256, 0, stream>>>(
      AOb, XNb, dec_b, (float*)d_out);
}